// Round 14
// baseline (8852.898 us; speedup 1.0000x reference)
//
#include <hip/hip_runtime.h>
#include <hip/hip_bf16.h>

typedef __bf16 bf16x8 __attribute__((ext_vector_type(8)));
typedef float  f32x4  __attribute__((ext_vector_type(4)));
typedef int    i32x4  __attribute__((ext_vector_type(4)));
typedef unsigned long long u64;

#define B_ 32
#define S_ 512
#define I_ 256
#define H_ 1024
#define O_ 256
#define M_ (B_*S_)   // 16384
#define OUT_ELEMS ((size_t)B_*S_*O_)   // 4194304
#define BH_ (B_*H_)  // one broadcast slot (elements)

#define MFMA16(A,Bf,C) __builtin_amdgcn_mfma_f32_16x16x32_bf16(A,Bf,C,0,0,0)

union V4 { i32x4 i; bf16x8 b; };

// CACHED burst (first attempt: shares one L2 fill per XCD when data present)
#define LD8C(P, V) asm volatile( \
  "global_load_dwordx4 %0, %8, off\n\t" \
  "global_load_dwordx4 %1, %8, off offset:64\n\t" \
  "global_load_dwordx4 %2, %8, off offset:128\n\t" \
  "global_load_dwordx4 %3, %8, off offset:192\n\t" \
  "global_load_dwordx4 %4, %8, off offset:256\n\t" \
  "global_load_dwordx4 %5, %8, off offset:320\n\t" \
  "global_load_dwordx4 %6, %8, off offset:384\n\t" \
  "global_load_dwordx4 %7, %8, off offset:448" \
  : "=&v"((V)[0].i),"=&v"((V)[1].i),"=&v"((V)[2].i),"=&v"((V)[3].i), \
    "=&v"((V)[4].i),"=&v"((V)[5].i),"=&v"((V)[6].i),"=&v"((V)[7].i) \
  : "v"(P) : "memory")

// MALL-direct burst (retry path: bypasses possibly-stale-sentinel L2 lines)
#define LD8S(P, V) asm volatile( \
  "global_load_dwordx4 %0, %8, off sc1\n\t" \
  "global_load_dwordx4 %1, %8, off offset:64 sc1\n\t" \
  "global_load_dwordx4 %2, %8, off offset:128 sc1\n\t" \
  "global_load_dwordx4 %3, %8, off offset:192 sc1\n\t" \
  "global_load_dwordx4 %4, %8, off offset:256 sc1\n\t" \
  "global_load_dwordx4 %5, %8, off offset:320 sc1\n\t" \
  "global_load_dwordx4 %6, %8, off offset:384 sc1\n\t" \
  "global_load_dwordx4 %7, %8, off offset:448 sc1" \
  : "=&v"((V)[0].i),"=&v"((V)[1].i),"=&v"((V)[2].i),"=&v"((V)[3].i), \
    "=&v"((V)[4].i),"=&v"((V)[5].i),"=&v"((V)[6].i),"=&v"((V)[7].i) \
  : "v"(P) : "memory")

#define WAITV() do { \
  asm volatile("s_waitcnt vmcnt(0)" ::: "memory"); \
  __builtin_amdgcn_sched_barrier(0); \
} while (0)

// sentinel check: each 8B producer store is atomic, so testing the low bf16
// of each u64 (0xFFFF = NaN, unproducible by the finite GRU arithmetic)
// decides whether that whole u64 has arrived.
__device__ __forceinline__ bool okv8(const V4* v) {
  bool ok = true;
#pragma unroll
  for (int i = 0; i < 8; ++i) {
    ok = ok && ((v[i].i[0] & 0xFFFF) != 0xFFFF);
    ok = ok && ((v[i].i[2] & 0xFFFF) != 0xFFFF);
  }
  return ok;
}

// writer side: agent-scope relaxed stores go straight to MALL (no dirty L2).
__device__ __forceinline__ void astore(__hip_bfloat16* p, u64 v) {
  __hip_atomic_store((u64*)p, v, __ATOMIC_RELAXED, __HIP_MEMORY_SCOPE_AGENT);
}
__device__ __forceinline__ unsigned short f2bf(float f) {
  __hip_bfloat16 h = __float2bfloat16(f);
  unsigned short s; __builtin_memcpy(&s, &h, 2); return s;
}

// ---------------- elementwise converts ----------------
__global__ void cvt_f32_bf16(const float* __restrict__ src, __hip_bfloat16* __restrict__ dst, int n) {
  for (int i = blockIdx.x*blockDim.x + threadIdx.x; i < n; i += gridDim.x*blockDim.x)
    dst[i] = __float2bfloat16(src[i]);
}

// x [B][S][I] f32 -> xb [S][B][I] bf16
__global__ void xpose_x(const float* __restrict__ x, __hip_bfloat16* __restrict__ xb) {
  const int total = B_*S_*I_;
  for (int d = blockIdx.x*blockDim.x + threadIdx.x; d < total; d += gridDim.x*blockDim.x) {
    int i = d & (I_-1);
    int b = (d >> 8) & (B_-1);
    int s = d >> 13;
    xb[d] = __float2bfloat16(x[((size_t)b*S_ + s)*I_ + i]);
  }
}

// ---------------- output GEMM: out[(b*S+s)*O+n] = A[m]*Yw^T + Yb ----------------
__global__ __launch_bounds__(256) void gemm_out(
    const __hip_bfloat16* __restrict__ A,   // [M][H] = hs2 slots 1..512
    const __hip_bfloat16* __restrict__ W,   // [O][H]
    float* __restrict__ dstf,
    const float* __restrict__ bias)
{
  __shared__ __hip_bfloat16 As[128][32];
  __shared__ __hip_bfloat16 Ws[64][32];
  const int tid  = threadIdx.x;
  const int wid  = tid >> 6, lane = tid & 63;
  const int m0   = blockIdx.y * 128, n0 = blockIdx.x * 64;
  const int col  = lane & 15, kl = (lane >> 4) * 8;
  const int lrow = tid >> 2, lcol = (tid & 3) * 8;
  f32x4 acc[2][4] = {};

  for (int k0 = 0; k0 < H_; k0 += 32) {
    __syncthreads();
    *(bf16x8*)&As[lrow][lcol]    = *(const bf16x8*)&A[(size_t)(m0+lrow)*H_    + k0 + lcol];
    *(bf16x8*)&As[lrow+64][lcol] = *(const bf16x8*)&A[(size_t)(m0+lrow+64)*H_ + k0 + lcol];
    *(bf16x8*)&Ws[lrow][lcol]    = *(const bf16x8*)&W[(size_t)(n0+lrow)*H_    + k0 + lcol];
    __syncthreads();
    bf16x8 a0 = *(const bf16x8*)&As[wid*32 + col][kl];
    bf16x8 a1 = *(const bf16x8*)&As[wid*32 + 16 + col][kl];
#pragma unroll
    for (int nt = 0; nt < 4; ++nt) {
      bf16x8 bw = *(const bf16x8*)&Ws[nt*16 + col][kl];
      acc[0][nt] = MFMA16(a0, bw, acc[0][nt]);
      acc[1][nt] = MFMA16(a1, bw, acc[1][nt]);
    }
  }
#pragma unroll
  for (int mt = 0; mt < 2; ++mt)
#pragma unroll
    for (int nt = 0; nt < 4; ++nt)
#pragma unroll
      for (int j = 0; j < 4; ++j) {
        int m = m0 + wid*32 + mt*16 + (lane>>4)*4 + j;
        int n = n0 + nt*16 + col;
        int s = m >> 5, b = m & 31;
        dstf[((size_t)b*S_ + s)*O_ + n] = acc[mt][nt][j] + bias[n];
      }
}

// ---------------- fused 2-layer persistent recurrence, FLAG-FREE ----------------
// Blocks 0..63 = layer 0, 64..127 = layer 1 (one step behind).
// All cross-block state in per-step UNIQUE slots, re-poisoned to 0xFF (bf16
// NaN) each launch. Producers fire sc1 u64 stores with NO drain and NO flag;
// consumers burst-load the exact data they need and retry (sc1) until no
// sentinel remains. Critical path = store->MALL->poll pickup (~1.5 RT/phase).
struct R2Args {
  const __hip_bfloat16 *xb;                      // [S][B][I]
  const __hip_bfloat16 *w1_0, *w2_0, *w1_1, *w2_1;
  const float *bz0,*br0,*bg0,*bz1,*br1,*bg1;
  const float *h0;                               // [B][2][H]
  __hip_bfloat16 *hs1;                           // [S+1][B][H]
  __hip_bfloat16 *hs2;                           // [S+1][B][H]
  __hip_bfloat16 *hr1;                           // [S][B][H]
  __hip_bfloat16 *hr2;                           // [S][B][H]
  float *fin;                                    // out + OUT_ELEMS
};

template<int LAY>
__device__ __forceinline__ void run_layer(const R2Args& a, int sub, int tid) {
  __shared__ f32x4 part[4][4][64];
  const int wid = tid >> 6, lane = tid & 63;
  const int col = lane & 15, kl = (lane >> 4) * 8;
  constexpr int K1 = LAY ? H_ : I_;     // W1 inner dim
  constexpr int NX = K1 / 128;          // x chunks per wave (8 or 2)

  __hip_bfloat16* hsO = LAY ? a.hs2 : a.hs1;     // own h history
  __hip_bfloat16* hrO = LAY ? a.hr2 : a.hr1;     // own hr history
  const __hip_bfloat16* W2 = LAY ? a.w2_1 : a.w2_0;
  const __hip_bfloat16* W1 = LAY ? a.w1_1 : a.w1_0;

  // ---- weights into VGPRs (cached; written by earlier dispatches) ----
  bf16x8 wz2[8], wr2[8], wg2[8], wz1[NX], wr1[NX], wg1[NX];
  {
    const __hip_bfloat16* wp = W2 + (size_t)(sub*16+col)*H_ + wid*256 + kl;
#pragma unroll
    for (int kc = 0; kc < 8; ++kc) {
      wz2[kc] = *(const bf16x8*)(wp + kc*32);
      wr2[kc] = *(const bf16x8*)(wp + (size_t)H_*H_   + kc*32);
      wg2[kc] = *(const bf16x8*)(wp + (size_t)2*H_*H_ + kc*32);
    }
    const __hip_bfloat16* qp = W1 + (size_t)(sub*16+col)*K1 + wid*(K1/4) + kl;
#pragma unroll
    for (int c = 0; c < NX; ++c) {
      wz1[c] = *(const bf16x8*)(qp + c*32);
      wr1[c] = *(const bf16x8*)(qp + (size_t)H_*K1   + c*32);
      wg1[c] = *(const bf16x8*)(qp + (size_t)2*H_*K1 + c*32);
    }
  }

  // ---- persistent state (epilogue threads wid<2) ----
  const int b   = wid*16 + (lane & 15);
  const int hh0 = sub*16 + (lane >> 4)*4;
  float hreg[4] = {0,0,0,0}, zreg[4] = {0,0,0,0};
  f32x4 bz4 = {0,0,0,0}, br4 = {0,0,0,0}, bg4 = {0,0,0,0};
  if (wid < 2) {
    bz4 = *(const f32x4*)((LAY ? a.bz1 : a.bz0) + hh0);
    br4 = *(const f32x4*)((LAY ? a.br1 : a.br0) + hh0);
    bg4 = *(const f32x4*)((LAY ? a.bg1 : a.bg0) + hh0);
    f32x4 h4 = *(const f32x4*)(a.h0 + (size_t)b*2048 + LAY*1024 + hh0);
#pragma unroll
    for (int j = 0; j < 4; ++j) hreg[j] = h4[j];
  }
  if (tid < 128) {   // publish slot 0 of own h history (sc1; consumers poll it)
    int bb = tid >> 2, hi = sub*16 + (tid & 3)*4;
    f32x4 v = *(const f32x4*)(a.h0 + (size_t)bb*2048 + LAY*1024 + hi);
    u64 pk = 0;
#pragma unroll
    for (int j = 0; j < 4; ++j) pk |= (u64)f2bf(v[j]) << (16*j);
    astore(&hsO[(size_t)bb*H_ + hi], pk);
  }

  for (int t = 0; t < S_; ++t) {
    f32x4 az0 = {0,0,0,0}, az1 = {0,0,0,0};
    f32x4 ar0 = {0,0,0,0}, ar1 = {0,0,0,0};
    f32x4 ag0 = {0,0,0,0}, ag1 = {0,0,0,0};

    // ---- L0: x-pass up front (plain cached input, always ready) ----
    if (LAY == 0) {
      const __hip_bfloat16* p0 = a.xb + (size_t)t*(B_*K1) + (size_t)col*K1 + wid*(K1/4) + kl;
      const __hip_bfloat16* p1 = p0 + (size_t)16*K1;
      bf16x8 xs0[NX], xs1[NX];
#pragma unroll
      for (int c = 0; c < NX; ++c) {
        xs0[c] = *(const bf16x8*)(p0 + c*32);
        xs1[c] = *(const bf16x8*)(p1 + c*32);
      }
#pragma unroll
      for (int c = 0; c < NX; ++c) {
        az0 = MFMA16(wz1[c], xs0[c], az0);  az1 = MFMA16(wz1[c], xs1[c], az1);
        ar0 = MFMA16(wr1[c], xs0[c], ar0);  ar1 = MFMA16(wr1[c], xs1[c], ar1);
        ag0 = MFMA16(wg1[c], xs0[c], ag0);  ag1 = MFMA16(wg1[c], xs1[c], ag1);
      }
    }

    // ---- phase A: data-poll h slot t (and, for L1, hs1 slot t+1) ----
    {
      const __hip_bfloat16* hp0 = hsO + (size_t)t*BH_ + (size_t)col*H_ + wid*256 + kl;
      const __hip_bfloat16* hp1 = hp0 + (size_t)16*H_;
      V4 HV0[8], HV1[8];
      if (LAY == 1) {
        const __hip_bfloat16* p0 = a.hs1 + (size_t)(t+1)*BH_ + (size_t)col*H_ + wid*256 + kl;
        const __hip_bfloat16* p1 = p0 + (size_t)16*H_;
        V4 XV0[8], XV1[8];
        LD8C(p0, XV0); LD8C(p1, XV1); LD8C(hp0, HV0); LD8C(hp1, HV1);
        WAITV();
        bool ok = okv8(XV0) && okv8(XV1) && okv8(HV0) && okv8(HV1);
        while (__any(!ok)) {
          __builtin_amdgcn_s_sleep(1);
          if (!ok) { LD8S(p0, XV0); LD8S(p1, XV1); LD8S(hp0, HV0); LD8S(hp1, HV1); }
          WAITV();
          ok = okv8(XV0) && okv8(XV1) && okv8(HV0) && okv8(HV1);
        }
#pragma unroll
        for (int c = 0; c < 8; ++c) {
          az0 = MFMA16(wz1[c], XV0[c].b, az0);  az1 = MFMA16(wz1[c], XV1[c].b, az1);
          ar0 = MFMA16(wr1[c], XV0[c].b, ar0);  ar1 = MFMA16(wr1[c], XV1[c].b, ar1);
          ag0 = MFMA16(wg1[c], XV0[c].b, ag0);  ag1 = MFMA16(wg1[c], XV1[c].b, ag1);
        }
      } else {
        LD8C(hp0, HV0); LD8C(hp1, HV1);
        WAITV();
        bool ok = okv8(HV0) && okv8(HV1);
        while (__any(!ok)) {
          __builtin_amdgcn_s_sleep(1);
          if (!ok) { LD8S(hp0, HV0); LD8S(hp1, HV1); }
          WAITV();
          ok = okv8(HV0) && okv8(HV1);
        }
      }
#pragma unroll
      for (int kc = 0; kc < 8; ++kc) {
        az0 = MFMA16(wz2[kc], HV0[kc].b, az0);  az1 = MFMA16(wz2[kc], HV1[kc].b, az1);
        ar0 = MFMA16(wr2[kc], HV0[kc].b, ar0);  ar1 = MFMA16(wr2[kc], HV1[kc].b, ar1);
      }
    }
    part[wid][0][lane] = az0; part[wid][1][lane] = az1;
    part[wid][2][lane] = ar0; part[wid][3][lane] = ar1;
    __syncthreads();
    if (wid < 2) {
      f32x4 zs = part[0][wid][lane] + part[1][wid][lane] + part[2][wid][lane] + part[3][wid][lane];
      f32x4 rs = part[0][2+wid][lane] + part[1][2+wid][lane] + part[2][2+wid][lane] + part[3][2+wid][lane];
      u64 pk = 0;
#pragma unroll
      for (int j = 0; j < 4; ++j) {
        float z = 1.f / (1.f + __expf(-(zs[j] + bz4[j])));
        float r = 1.f / (1.f + __expf(-(rs[j] + br4[j])));
        zreg[j] = z;
        pk |= (u64)f2bf(r * hreg[j]) << (16*j);
      }
      astore(&hrO[(size_t)t*BH_ + (size_t)b*H_ + hh0], pk);   // fire & forget
    }
    __syncthreads();                      // LDS part[] reuse hazard only

    // ---- phase B: data-poll hr slot t; g += W2g*(r.h); h update ----
    {
      const __hip_bfloat16* hp0 = hrO + (size_t)t*BH_ + (size_t)col*H_ + wid*256 + kl;
      const __hip_bfloat16* hp1 = hp0 + (size_t)16*H_;
      V4 RV0[8], RV1[8];
      LD8C(hp0, RV0); LD8C(hp1, RV1);
      WAITV();
      bool ok = okv8(RV0) && okv8(RV1);
      while (__any(!ok)) {
        __builtin_amdgcn_s_sleep(1);
        if (!ok) { LD8S(hp0, RV0); LD8S(hp1, RV1); }
        WAITV();
        ok = okv8(RV0) && okv8(RV1);
      }
#pragma unroll
      for (int kc = 0; kc < 8; ++kc) {
        ag0 = MFMA16(wg2[kc], RV0[kc].b, ag0);
        ag1 = MFMA16(wg2[kc], RV1[kc].b, ag1);
      }
    }
    part[wid][0][lane] = ag0; part[wid][1][lane] = ag1;
    __syncthreads();
    if (wid < 2) {
      f32x4 gs = part[0][wid][lane] + part[1][wid][lane] + part[2][wid][lane] + part[3][wid][lane];
      u64 pk = 0; f32x4 fv;
#pragma unroll
      for (int j = 0; j < 4; ++j) {
        float g  = tanhf(gs[j] + bg4[j]);
        float hn = zreg[j]*hreg[j] + (1.f - zreg[j])*g;
        hreg[j] = hn; fv[j] = hn;
        pk |= (u64)f2bf(hn) << (16*j);
      }
      astore(&hsO[(size_t)(t+1)*BH_ + (size_t)b*H_ + hh0], pk);   // fire & forget
      if (t == S_-2) *(f32x4*)(a.fin + LAY*1024 + (size_t)b*2048 + hh0) = fv;
    }
    __syncthreads();                      // LDS part[] reuse hazard only
  }
}

__global__ __launch_bounds__(256, 1) void recur2(R2Args a) {
  const int lay = blockIdx.x >> 6, sub = blockIdx.x & 63;
  if (lay == 0) run_layer<0>(a, sub, threadIdx.x);
  else          run_layer<1>(a, sub, threadIdx.x);
}

// ---------------- host ----------------
extern "C" void kernel_launch(void* const* d_in, const int* in_sizes, int n_in,
                              void* d_out, int out_size, void* d_ws, size_t ws_size,
                              hipStream_t stream) {
  (void)in_sizes; (void)n_in; (void)out_size; (void)ws_size;
  const float* x     = (const float*)d_in[0];
  const float* hid0  = (const float*)d_in[1];
  const float* z1_0  = (const float*)d_in[2];
  const float* z2_0  = (const float*)d_in[3];
  const float* z2b_0 = (const float*)d_in[4];
  const float* r1_0  = (const float*)d_in[5];
  const float* r2_0  = (const float*)d_in[6];
  const float* r2b_0 = (const float*)d_in[7];
  const float* g1_0  = (const float*)d_in[8];
  const float* g2_0  = (const float*)d_in[9];
  const float* g2b_0 = (const float*)d_in[10];
  const float* z1_1  = (const float*)d_in[11];
  const float* z2_1  = (const float*)d_in[12];
  const float* z2b_1 = (const float*)d_in[13];
  const float* r1_1  = (const float*)d_in[14];
  const float* r2_1  = (const float*)d_in[15];
  const float* r2b_1 = (const float*)d_in[16];
  const float* g1_1  = (const float*)d_in[17];
  const float* g2_1  = (const float*)d_in[18];
  const float* g2b_1 = (const float*)d_in[19];
  const float* Yw    = (const float*)d_in[20];
  const float* Yb    = (const float*)d_in[21];
  float* out = (float*)d_out;

  char* ws = (char*)d_ws;
  size_t off = 0;
  auto alloc = [&](size_t bytes) -> void* {
    void* p = ws + off; off += (bytes + 255) & ~(size_t)255; return p;
  };
  __hip_bfloat16* hs1   = (__hip_bfloat16*)alloc((size_t)(S_+1)*BH_*2);  // 33.6 MB
  __hip_bfloat16* hs2   = (__hip_bfloat16*)alloc((size_t)(S_+1)*BH_*2);  // 33.6 MB
  __hip_bfloat16* hr1   = (__hip_bfloat16*)alloc((size_t)S_*BH_*2);      // 32 MB
  __hip_bfloat16* hr2   = (__hip_bfloat16*)alloc((size_t)S_*BH_*2);      // 32 MB
  __hip_bfloat16* xb    = (__hip_bfloat16*)alloc((size_t)M_*I_*2);       // 8 MB
  __hip_bfloat16* w1p0  = (__hip_bfloat16*)alloc((size_t)3*H_*I_*2);
  __hip_bfloat16* w1p1  = (__hip_bfloat16*)alloc((size_t)3*H_*H_*2);
  __hip_bfloat16* w2p0  = (__hip_bfloat16*)alloc((size_t)3*H_*H_*2);
  __hip_bfloat16* w2p1  = (__hip_bfloat16*)alloc((size_t)3*H_*H_*2);
  __hip_bfloat16* ywp   = (__hip_bfloat16*)alloc((size_t)O_*H_*2);

  // re-poison broadcast slots to bf16 NaN (0xFFFF) every launch/replay
  hipMemsetAsync(hs1, 0xFF, (size_t)(S_+1)*BH_*2, stream);
  hipMemsetAsync(hs2, 0xFF, (size_t)(S_+1)*BH_*2, stream);
  hipMemsetAsync(hr1, 0xFF, (size_t)S_*BH_*2, stream);
  hipMemsetAsync(hr2, 0xFF, (size_t)S_*BH_*2, stream);

  hipLaunchKernelGGL(xpose_x, dim3(2048), dim3(256), 0, stream, x, xb);
  auto CVT = [&](const float* s, __hip_bfloat16* d, int n) {
    hipLaunchKernelGGL(cvt_f32_bf16, dim3(512), dim3(256), 0, stream, s, d, n);
  };
  CVT(z1_0, w1p0,            H_*I_);
  CVT(r1_0, w1p0 + H_*I_,    H_*I_);
  CVT(g1_0, w1p0 + 2*H_*I_,  H_*I_);
  CVT(z2_0, w2p0,            H_*H_);
  CVT(r2_0, w2p0 + H_*H_,    H_*H_);
  CVT(g2_0, w2p0 + 2*H_*H_,  H_*H_);
  CVT(z1_1, w1p1,            H_*H_);
  CVT(r1_1, w1p1 + H_*H_,    H_*H_);
  CVT(g1_1, w1p1 + 2*H_*H_,  H_*H_);
  CVT(z2_1, w2p1,            H_*H_);
  CVT(r2_1, w2p1 + H_*H_,    H_*H_);
  CVT(g2_1, w2p1 + 2*H_*H_,  H_*H_);
  CVT(Yw,   ywp,             O_*H_);

  R2Args ra;
  ra.xb = xb;
  ra.w1_0 = w1p0; ra.w2_0 = w2p0; ra.w1_1 = w1p1; ra.w2_1 = w2p1;
  ra.bz0 = z2b_0; ra.br0 = r2b_0; ra.bg0 = g2b_0;
  ra.bz1 = z2b_1; ra.br1 = r2b_1; ra.bg1 = g2b_1;
  ra.h0 = hid0;
  ra.hs1 = hs1; ra.hs2 = hs2; ra.hr1 = hr1; ra.hr2 = hr2;
  ra.fin = out + OUT_ELEMS;
  hipLaunchKernelGGL(recur2, dim3(128), dim3(256), 0, stream, ra);

  // output projection + bias (A = hs2 slots 1..512)
  hipLaunchKernelGGL(gemm_out, dim3(4, 128), dim3(256), 0, stream,
                     hs2 + BH_, ywp, out, Yb);
}

// Round 15
// 5702.560 us; speedup vs baseline: 1.5524x; 1.5524x over previous
//
#include <hip/hip_runtime.h>
#include <hip/hip_bf16.h>

typedef __bf16 bf16x8 __attribute__((ext_vector_type(8)));
typedef float  f32x4  __attribute__((ext_vector_type(4)));
typedef int    i32x4  __attribute__((ext_vector_type(4)));
typedef unsigned long long u64;

#define B_ 32
#define S_ 512
#define I_ 256
#define H_ 1024
#define O_ 256
#define M_ (B_*S_)   // 16384
#define OUT_ELEMS ((size_t)B_*S_*O_)   // 4194304
#define BH_ (B_*H_)  // one broadcast slot (elements)
#define FSTR 64      // flag stride in uints: one flag per 256B line

#define MFMA16(A,Bf,C) __builtin_amdgcn_mfma_f32_16x16x32_bf16(A,Bf,C,0,0,0)

union V4 { i32x4 i; bf16x8 b; };

// CACHED burst: 8 x dwordx4, stride 64B, one latency per batch. Safe because
// broadcast addresses are written exactly once (before any read) per dispatch.
#define LD8C(P, V) asm volatile( \
  "global_load_dwordx4 %0, %8, off\n\t" \
  "global_load_dwordx4 %1, %8, off offset:64\n\t" \
  "global_load_dwordx4 %2, %8, off offset:128\n\t" \
  "global_load_dwordx4 %3, %8, off offset:192\n\t" \
  "global_load_dwordx4 %4, %8, off offset:256\n\t" \
  "global_load_dwordx4 %5, %8, off offset:320\n\t" \
  "global_load_dwordx4 %6, %8, off offset:384\n\t" \
  "global_load_dwordx4 %7, %8, off offset:448" \
  : "=&v"((V)[0].i),"=&v"((V)[1].i),"=&v"((V)[2].i),"=&v"((V)[3].i), \
    "=&v"((V)[4].i),"=&v"((V)[5].i),"=&v"((V)[6].i),"=&v"((V)[7].i) \
  : "v"(P) : "memory")

#define WAITV() do { \
  asm volatile("s_waitcnt vmcnt(0)" ::: "memory"); \
  __builtin_amdgcn_sched_barrier(0); \
} while (0)

// writer side: agent-scope relaxed stores go straight to MALL (no dirty L2).
__device__ __forceinline__ void astore(__hip_bfloat16* p, u64 v) {
  __hip_atomic_store((u64*)p, v, __ATOMIC_RELAXED, __HIP_MEMORY_SCOPE_AGENT);
}
__device__ __forceinline__ unsigned int aload32(const unsigned int* p) {
  return __hip_atomic_load(p, __ATOMIC_RELAXED, __HIP_MEMORY_SCOPE_AGENT);
}
__device__ __forceinline__ void astore32(unsigned int* p, unsigned int v) {
  __hip_atomic_store(p, v, __ATOMIC_RELAXED, __HIP_MEMORY_SCOPE_AGENT);
}
__device__ __forceinline__ unsigned short f2bf(float f) {
  __hip_bfloat16 h = __float2bfloat16(f);
  unsigned short s; __builtin_memcpy(&s, &h, 2); return s;
}

// ---------------- elementwise converts ----------------
__global__ void cvt_f32_bf16(const float* __restrict__ src, __hip_bfloat16* __restrict__ dst, int n) {
  for (int i = blockIdx.x*blockDim.x + threadIdx.x; i < n; i += gridDim.x*blockDim.x)
    dst[i] = __float2bfloat16(src[i]);
}

// x [B][S][I] f32 -> xb [S][B][I] bf16
__global__ void xpose_x(const float* __restrict__ x, __hip_bfloat16* __restrict__ xb) {
  const int total = B_*S_*I_;
  for (int d = blockIdx.x*blockDim.x + threadIdx.x; d < total; d += gridDim.x*blockDim.x) {
    int i = d & (I_-1);
    int b = (d >> 8) & (B_-1);
    int s = d >> 13;
    xb[d] = __float2bfloat16(x[((size_t)b*S_ + s)*I_ + i]);
  }
}

// ---------------- output GEMM: out[(b*S+s)*O+n] = A[m]*Yw^T + Yb ----------------
__global__ __launch_bounds__(256) void gemm_out(
    const __hip_bfloat16* __restrict__ A,   // [M][H] = hs2 slots 1..512
    const __hip_bfloat16* __restrict__ W,   // [O][H]
    float* __restrict__ dstf,
    const float* __restrict__ bias)
{
  __shared__ __hip_bfloat16 As[128][32];
  __shared__ __hip_bfloat16 Ws[64][32];
  const int tid  = threadIdx.x;
  const int wid  = tid >> 6, lane = tid & 63;
  const int m0   = blockIdx.y * 128, n0 = blockIdx.x * 64;
  const int col  = lane & 15, kl = (lane >> 4) * 8;
  const int lrow = tid >> 2, lcol = (tid & 3) * 8;
  f32x4 acc[2][4] = {};

  for (int k0 = 0; k0 < H_; k0 += 32) {
    __syncthreads();
    *(bf16x8*)&As[lrow][lcol]    = *(const bf16x8*)&A[(size_t)(m0+lrow)*H_    + k0 + lcol];
    *(bf16x8*)&As[lrow+64][lcol] = *(const bf16x8*)&A[(size_t)(m0+lrow+64)*H_ + k0 + lcol];
    *(bf16x8*)&Ws[lrow][lcol]    = *(const bf16x8*)&W[(size_t)(n0+lrow)*H_    + k0 + lcol];
    __syncthreads();
    bf16x8 a0 = *(const bf16x8*)&As[wid*32 + col][kl];
    bf16x8 a1 = *(const bf16x8*)&As[wid*32 + 16 + col][kl];
#pragma unroll
    for (int nt = 0; nt < 4; ++nt) {
      bf16x8 bw = *(const bf16x8*)&Ws[nt*16 + col][kl];
      acc[0][nt] = MFMA16(a0, bw, acc[0][nt]);
      acc[1][nt] = MFMA16(a1, bw, acc[1][nt]);
    }
  }
#pragma unroll
  for (int mt = 0; mt < 2; ++mt)
#pragma unroll
    for (int nt = 0; nt < 4; ++nt)
#pragma unroll
      for (int j = 0; j < 4; ++j) {
        int m = m0 + wid*32 + mt*16 + (lane>>4)*4 + j;
        int n = n0 + nt*16 + col;
        int s = m >> 5, b = m & 31;
        dstf[((size_t)b*S_ + s)*O_ + n] = acc[mt][nt][j] + bias[n];
      }
}

// ---------------- fused 2-layer persistent recurrence ----------------
// Blocks 0..63 = layer 0, 64..127 = layer 1 (one step behind).
// Broadcast state in per-step UNIQUE slots (sc1 writes, cached reads) — r13.
// NEW vs r13: (1) split flags per epilogue wave (fhA/fhB, frA/frB): each wave
// drains ITS OWN stores (vmcnt is per-wave) and publishes immediately — the
// block-wide syncthreads leaves the publish critical path. (2) dependency
// polls run in waves 2/3 CONCURRENTLY with waves 0/1's epilogue; top-of-loop
// waits vanish (prologue seeds t=0).
// Epochs: fh = h slots published (init 1; sec4 of step t -> t+2).
//         fr = hr slots published (sec2 of step t -> t+1).
struct R2Args {
  const __hip_bfloat16 *xb;                      // [S][B][I]
  const __hip_bfloat16 *w1_0, *w2_0, *w1_1, *w2_1;
  const float *bz0,*br0,*bg0,*bz1,*br1,*bg1;
  const float *h0;                               // [B][2][H]
  __hip_bfloat16 *hs1;                           // [S+1][B][H]
  __hip_bfloat16 *hs2;                           // [S+1][B][H]
  __hip_bfloat16 *hr1;                           // [S][B][H]
  __hip_bfloat16 *hr2;                           // [S][B][H]
  float *fin;                                    // out + OUT_ELEMS
  unsigned int *fl;                              // [2 layers][4 arrays][64][FSTR]
};

template<int LAY>
__device__ __forceinline__ void run_layer(const R2Args& a, int sub, int tid) {
  __shared__ f32x4 part[4][4][64];
  const int wid = tid >> 6, lane = tid & 63;
  const int col = lane & 15, kl = (lane >> 4) * 8;
  constexpr int K1 = LAY ? H_ : I_;     // W1 inner dim
  constexpr int NX = K1 / 128;          // x chunks per wave (8 or 2)

  unsigned int* flL = a.fl + (size_t)LAY*(4*64*FSTR);
  unsigned int* fhA = flL;               // h half A (b 0-15)
  unsigned int* fhB = flL + 64*FSTR;     // h half B (b 16-31)
  unsigned int* frA = flL + 128*FSTR;    // hr half A
  unsigned int* frB = flL + 192*FSTR;    // hr half B
  const unsigned int* fhA0 = a.fl;             // layer-0 h flags (L1's x dep)
  const unsigned int* fhB0 = a.fl + 64*FSTR;

  __hip_bfloat16* hsO = LAY ? a.hs2 : a.hs1;     // own h history
  __hip_bfloat16* hrO = LAY ? a.hr2 : a.hr1;     // own hr history
  const __hip_bfloat16* W2 = LAY ? a.w2_1 : a.w2_0;
  const __hip_bfloat16* W1 = LAY ? a.w1_1 : a.w1_0;

  // ---- weights into VGPRs (cached; written by earlier dispatches) ----
  bf16x8 wz2[8], wr2[8], wg2[8], wz1[NX], wr1[NX], wg1[NX];
  {
    const __hip_bfloat16* wp = W2 + (size_t)(sub*16+col)*H_ + wid*256 + kl;
#pragma unroll
    for (int kc = 0; kc < 8; ++kc) {
      wz2[kc] = *(const bf16x8*)(wp + kc*32);
      wr2[kc] = *(const bf16x8*)(wp + (size_t)H_*H_   + kc*32);
      wg2[kc] = *(const bf16x8*)(wp + (size_t)2*H_*H_ + kc*32);
    }
    const __hip_bfloat16* qp = W1 + (size_t)(sub*16+col)*K1 + wid*(K1/4) + kl;
#pragma unroll
    for (int c = 0; c < NX; ++c) {
      wz1[c] = *(const bf16x8*)(qp + c*32);
      wr1[c] = *(const bf16x8*)(qp + (size_t)H_*K1   + c*32);
      wg1[c] = *(const bf16x8*)(qp + (size_t)2*H_*K1 + c*32);
    }
  }

  // ---- persistent state (epilogue threads wid<2) ----
  const int b   = wid*16 + (lane & 15);
  const int hh0 = sub*16 + (lane >> 4)*4;
  float hreg[4] = {0,0,0,0}, zreg[4] = {0,0,0,0};
  f32x4 bz4 = {0,0,0,0}, br4 = {0,0,0,0}, bg4 = {0,0,0,0};
  if (wid < 2) {
    bz4 = *(const f32x4*)((LAY ? a.bz1 : a.bz0) + hh0);
    br4 = *(const f32x4*)((LAY ? a.br1 : a.br0) + hh0);
    bg4 = *(const f32x4*)((LAY ? a.bg1 : a.bg0) + hh0);
    f32x4 h4 = *(const f32x4*)(a.h0 + (size_t)b*2048 + LAY*1024 + hh0);
#pragma unroll
    for (int j = 0; j < 4; ++j) hreg[j] = h4[j];
    // publish slot 0 of own h history (same lane mapping as epilogue-B)
    u64 pk = 0;
#pragma unroll
    for (int j = 0; j < 4; ++j) pk |= (u64)f2bf(h4[j]) << (16*j);
    astore(&hsO[(size_t)b*H_ + hh0], pk);
    asm volatile("s_waitcnt vmcnt(0)" ::: "memory");
    if (lane == 0) astore32((wid ? fhB : fhA) + sub*FSTR, 1u);
  }
  // prologue polls: seed the t=0 dependencies
  if (wid == 2) {
    while (aload32(&fhA[lane*FSTR]) < 1u || aload32(&fhB[lane*FSTR]) < 1u)
      __builtin_amdgcn_s_sleep(2);
  } else if (LAY == 1 && wid == 3) {
    while (aload32(&fhA0[lane*FSTR]) < 2u || aload32(&fhB0[lane*FSTR]) < 2u)
      __builtin_amdgcn_s_sleep(2);
  }
  __syncthreads();

  for (int t = 0; t < S_; ++t) {
    f32x4 az0 = {0,0,0,0}, az1 = {0,0,0,0};
    f32x4 ar0 = {0,0,0,0}, ar1 = {0,0,0,0};
    f32x4 ag0 = {0,0,0,0}, ag1 = {0,0,0,0};

    // ---- sec0 (L0 only): x-pass, plain cached input, always ready ----
    if (LAY == 0) {
      const __hip_bfloat16* p0 = a.xb + (size_t)t*(B_*K1) + (size_t)col*K1 + wid*(K1/4) + kl;
      const __hip_bfloat16* p1 = p0 + (size_t)16*K1;
      bf16x8 xs0[NX], xs1[NX];
#pragma unroll
      for (int c = 0; c < NX; ++c) {
        xs0[c] = *(const bf16x8*)(p0 + c*32);
        xs1[c] = *(const bf16x8*)(p1 + c*32);
      }
#pragma unroll
      for (int c = 0; c < NX; ++c) {
        az0 = MFMA16(wz1[c], xs0[c], az0);  az1 = MFMA16(wz1[c], xs1[c], az1);
        ar0 = MFMA16(wr1[c], xs0[c], ar0);  ar1 = MFMA16(wr1[c], xs1[c], ar1);
        ag0 = MFMA16(wg1[c], xs0[c], ag0);  ag1 = MFMA16(wg1[c], xs1[c], ag1);
      }
    }

    // ---- sec1: phase-A bursts + MFMAs (deps verified by prior sec4/prologue) ----
    {
      const __hip_bfloat16* hp0 = hsO + (size_t)t*BH_ + (size_t)col*H_ + wid*256 + kl;
      const __hip_bfloat16* hp1 = hp0 + (size_t)16*H_;
      V4 HV0[8], HV1[8];
      if (LAY == 1) {
        const __hip_bfloat16* p0 = a.hs1 + (size_t)(t+1)*BH_ + (size_t)col*H_ + wid*256 + kl;
        const __hip_bfloat16* p1 = p0 + (size_t)16*H_;
        V4 XV0[8], XV1[8];
        LD8C(p0, XV0); LD8C(p1, XV1);
        LD8C(hp0, HV0); LD8C(hp1, HV1);
        WAITV();
#pragma unroll
        for (int c = 0; c < 8; ++c) {
          az0 = MFMA16(wz1[c], XV0[c].b, az0);  az1 = MFMA16(wz1[c], XV1[c].b, az1);
          ar0 = MFMA16(wr1[c], XV0[c].b, ar0);  ar1 = MFMA16(wr1[c], XV1[c].b, ar1);
          ag0 = MFMA16(wg1[c], XV0[c].b, ag0);  ag1 = MFMA16(wg1[c], XV1[c].b, ag1);
        }
      } else {
        LD8C(hp0, HV0); LD8C(hp1, HV1);
        WAITV();
      }
#pragma unroll
      for (int kc = 0; kc < 8; ++kc) {
        az0 = MFMA16(wz2[kc], HV0[kc].b, az0);  az1 = MFMA16(wz2[kc], HV1[kc].b, az1);
        ar0 = MFMA16(wr2[kc], HV0[kc].b, ar0);  ar1 = MFMA16(wr2[kc], HV1[kc].b, ar1);
      }
    }
    part[wid][0][lane] = az0; part[wid][1][lane] = az1;
    part[wid][2][lane] = ar0; part[wid][3][lane] = ar1;
    __syncthreads();

    // ---- sec2: epilogue-A (waves 0/1) ∥ fr-poll (wave 2) ----
    if (wid < 2) {
      f32x4 zs = part[0][wid][lane] + part[1][wid][lane] + part[2][wid][lane] + part[3][wid][lane];
      f32x4 rs = part[0][2+wid][lane] + part[1][2+wid][lane] + part[2][2+wid][lane] + part[3][2+wid][lane];
      u64 pk = 0;
#pragma unroll
      for (int j = 0; j < 4; ++j) {
        float z = 1.f / (1.f + __expf(-(zs[j] + bz4[j])));
        float r = 1.f / (1.f + __expf(-(rs[j] + br4[j])));
        zreg[j] = z;
        pk |= (u64)f2bf(r * hreg[j]) << (16*j);
      }
      astore(&hrO[(size_t)t*BH_ + (size_t)b*H_ + hh0], pk);
      asm volatile("s_waitcnt vmcnt(0)" ::: "memory");   // per-wave drain
      if (lane == 0) astore32((wid ? frB : frA) + sub*FSTR, (unsigned)(t + 1));
    } else if (wid == 2) {
      unsigned tgt = (unsigned)(t + 1);
      while (aload32(&frA[lane*FSTR]) < tgt || aload32(&frB[lane*FSTR]) < tgt)
        __builtin_amdgcn_s_sleep(2);
    }
    __syncthreads();

    // ---- sec3: phase-B burst + MFMAs ----
    {
      const __hip_bfloat16* hp0 = hrO + (size_t)t*BH_ + (size_t)col*H_ + wid*256 + kl;
      const __hip_bfloat16* hp1 = hp0 + (size_t)16*H_;
      V4 RV0[8], RV1[8];
      LD8C(hp0, RV0); LD8C(hp1, RV1);
      WAITV();
#pragma unroll
      for (int kc = 0; kc < 8; ++kc) {
        ag0 = MFMA16(wg2[kc], RV0[kc].b, ag0);
        ag1 = MFMA16(wg2[kc], RV1[kc].b, ag1);
      }
    }
    part[wid][0][lane] = ag0; part[wid][1][lane] = ag1;
    __syncthreads();

    // ---- sec4: epilogue-B (waves 0/1) ∥ fh-poll (wave 2) ∥ L0-x poll (wave 3) ----
    if (wid < 2) {
      f32x4 gs = part[0][wid][lane] + part[1][wid][lane] + part[2][wid][lane] + part[3][wid][lane];
      u64 pk = 0; f32x4 fv;
#pragma unroll
      for (int j = 0; j < 4; ++j) {
        float g  = tanhf(gs[j] + bg4[j]);
        float hn = zreg[j]*hreg[j] + (1.f - zreg[j])*g;
        hreg[j] = hn; fv[j] = hn;
        pk |= (u64)f2bf(hn) << (16*j);
      }
      astore(&hsO[(size_t)(t+1)*BH_ + (size_t)b*H_ + hh0], pk);   // the ONLY h store
      if (t == S_-2) *(f32x4*)(a.fin + LAY*1024 + (size_t)b*2048 + hh0) = fv;
      asm volatile("s_waitcnt vmcnt(0)" ::: "memory");   // per-wave drain
      if (lane == 0) astore32((wid ? fhB : fhA) + sub*FSTR, (unsigned)(t + 2));
    } else if (wid == 2) {
      unsigned tgt = (unsigned)(t + 2);                  // next step's h dep
      while (aload32(&fhA[lane*FSTR]) < tgt || aload32(&fhB[lane*FSTR]) < tgt)
        __builtin_amdgcn_s_sleep(2);
    } else if (LAY == 1 && wid == 3 && t < S_-1) {
      unsigned tgt = (unsigned)(t + 3);                  // next step's x dep
      while (aload32(&fhA0[lane*FSTR]) < tgt || aload32(&fhB0[lane*FSTR]) < tgt)
        __builtin_amdgcn_s_sleep(2);
    }
    __syncthreads();
  }
}

__global__ __launch_bounds__(256, 1) void recur2(R2Args a) {
  const int lay = blockIdx.x >> 6, sub = blockIdx.x & 63;
  if (lay == 0) run_layer<0>(a, sub, threadIdx.x);
  else          run_layer<1>(a, sub, threadIdx.x);
}

// ---------------- host ----------------
extern "C" void kernel_launch(void* const* d_in, const int* in_sizes, int n_in,
                              void* d_out, int out_size, void* d_ws, size_t ws_size,
                              hipStream_t stream) {
  (void)in_sizes; (void)n_in; (void)out_size; (void)ws_size;
  const float* x     = (const float*)d_in[0];
  const float* hid0  = (const float*)d_in[1];
  const float* z1_0  = (const float*)d_in[2];
  const float* z2_0  = (const float*)d_in[3];
  const float* z2b_0 = (const float*)d_in[4];
  const float* r1_0  = (const float*)d_in[5];
  const float* r2_0  = (const float*)d_in[6];
  const float* r2b_0 = (const float*)d_in[7];
  const float* g1_0  = (const float*)d_in[8];
  const float* g2_0  = (const float*)d_in[9];
  const float* g2b_0 = (const float*)d_in[10];
  const float* z1_1  = (const float*)d_in[11];
  const float* z2_1  = (const float*)d_in[12];
  const float* z2b_1 = (const float*)d_in[13];
  const float* r1_1  = (const float*)d_in[14];
  const float* r2_1  = (const float*)d_in[15];
  const float* r2b_1 = (const float*)d_in[16];
  const float* g1_1  = (const float*)d_in[17];
  const float* g2_1  = (const float*)d_in[18];
  const float* g2b_1 = (const float*)d_in[19];
  const float* Yw    = (const float*)d_in[20];
  const float* Yb    = (const float*)d_in[21];
  float* out = (float*)d_out;

  char* ws = (char*)d_ws;
  size_t off = 0;
  auto alloc = [&](size_t bytes) -> void* {
    void* p = ws + off; off += (bytes + 255) & ~(size_t)255; return p;
  };
  __hip_bfloat16* hs1   = (__hip_bfloat16*)alloc((size_t)(S_+1)*BH_*2);  // 33.6 MB
  __hip_bfloat16* hs2   = (__hip_bfloat16*)alloc((size_t)(S_+1)*BH_*2);  // 33.6 MB
  __hip_bfloat16* hr1   = (__hip_bfloat16*)alloc((size_t)S_*BH_*2);      // 32 MB
  __hip_bfloat16* hr2   = (__hip_bfloat16*)alloc((size_t)S_*BH_*2);      // 32 MB
  __hip_bfloat16* xb    = (__hip_bfloat16*)alloc((size_t)M_*I_*2);       // 8 MB
  __hip_bfloat16* w1p0  = (__hip_bfloat16*)alloc((size_t)3*H_*I_*2);
  __hip_bfloat16* w1p1  = (__hip_bfloat16*)alloc((size_t)3*H_*H_*2);
  __hip_bfloat16* w2p0  = (__hip_bfloat16*)alloc((size_t)3*H_*H_*2);
  __hip_bfloat16* w2p1  = (__hip_bfloat16*)alloc((size_t)3*H_*H_*2);
  __hip_bfloat16* ywp   = (__hip_bfloat16*)alloc((size_t)O_*H_*2);
  unsigned int*   bars  = (unsigned int*)  alloc((size_t)2*4*64*FSTR*4); // 128 KB flags

  hipMemsetAsync(bars, 0, (size_t)2*4*64*FSTR*4, stream);

  hipLaunchKernelGGL(xpose_x, dim3(2048), dim3(256), 0, stream, x, xb);
  auto CVT = [&](const float* s, __hip_bfloat16* d, int n) {
    hipLaunchKernelGGL(cvt_f32_bf16, dim3(512), dim3(256), 0, stream, s, d, n);
  };
  CVT(z1_0, w1p0,            H_*I_);
  CVT(r1_0, w1p0 + H_*I_,    H_*I_);
  CVT(g1_0, w1p0 + 2*H_*I_,  H_*I_);
  CVT(z2_0, w2p0,            H_*H_);
  CVT(r2_0, w2p0 + H_*H_,    H_*H_);
  CVT(g2_0, w2p0 + 2*H_*H_,  H_*H_);
  CVT(z1_1, w1p1,            H_*H_);
  CVT(r1_1, w1p1 + H_*H_,    H_*H_);
  CVT(g1_1, w1p1 + 2*H_*H_,  H_*H_);
  CVT(z2_1, w2p1,            H_*H_);
  CVT(r2_1, w2p1 + H_*H_,    H_*H_);
  CVT(g2_1, w2p1 + 2*H_*H_,  H_*H_);
  CVT(Yw,   ywp,             O_*H_);

  R2Args ra;
  ra.xb = xb;
  ra.w1_0 = w1p0; ra.w2_0 = w2p0; ra.w1_1 = w1p1; ra.w2_1 = w2p1;
  ra.bz0 = z2b_0; ra.br0 = r2b_0; ra.bg0 = g2b_0;
  ra.bz1 = z2b_1; ra.br1 = r2b_1; ra.bg1 = g2b_1;
  ra.h0 = hid0;
  ra.hs1 = hs1; ra.hs2 = hs2; ra.hr1 = hr1; ra.hr2 = hr2;
  ra.fin = out + OUT_ELEMS;
  ra.fl = bars;
  hipLaunchKernelGGL(recur2, dim3(128), dim3(256), 0, stream, ra);

  // output projection + bias (A = hs2 slots 1..512)
  hipLaunchKernelGGL(gemm_out, dim3(4, 128), dim3(256), 0, stream,
                     hs2 + BH_, ywp, out, Yb);
}

// Round 16
// 4851.006 us; speedup vs baseline: 1.8250x; 1.1755x over previous
//
#include <hip/hip_runtime.h>
#include <hip/hip_bf16.h>

typedef __bf16 bf16x8 __attribute__((ext_vector_type(8)));
typedef float  f32x4  __attribute__((ext_vector_type(4)));
typedef int    i32x4  __attribute__((ext_vector_type(4)));
typedef unsigned long long u64;

#define B_ 32
#define S_ 512
#define I_ 256
#define H_ 1024
#define O_ 256
#define M_ (B_*S_)   // 16384
#define OUT_ELEMS ((size_t)B_*S_*O_)   // 4194304
#define BH_ (B_*H_)  // one broadcast slot (elements)
#define FSTR 64      // flag stride in uints: one flag per 256B line

#define MFMA16(A,Bf,C) __builtin_amdgcn_mfma_f32_16x16x32_bf16(A,Bf,C,0,0,0)

union V4 { i32x4 i; bf16x8 b; };

// CACHED burst: 8 x dwordx4, stride 64B, one latency per batch. Safe because
// broadcast addresses are written exactly once (before any read) per dispatch.
#define LD8C(P, V) asm volatile( \
  "global_load_dwordx4 %0, %8, off\n\t" \
  "global_load_dwordx4 %1, %8, off offset:64\n\t" \
  "global_load_dwordx4 %2, %8, off offset:128\n\t" \
  "global_load_dwordx4 %3, %8, off offset:192\n\t" \
  "global_load_dwordx4 %4, %8, off offset:256\n\t" \
  "global_load_dwordx4 %5, %8, off offset:320\n\t" \
  "global_load_dwordx4 %6, %8, off offset:384\n\t" \
  "global_load_dwordx4 %7, %8, off offset:448" \
  : "=&v"((V)[0].i),"=&v"((V)[1].i),"=&v"((V)[2].i),"=&v"((V)[3].i), \
    "=&v"((V)[4].i),"=&v"((V)[5].i),"=&v"((V)[6].i),"=&v"((V)[7].i) \
  : "v"(P) : "memory")

#define WAITV() do { \
  asm volatile("s_waitcnt vmcnt(0)" ::: "memory"); \
  __builtin_amdgcn_sched_barrier(0); \
} while (0)

// writer side: agent-scope relaxed stores go straight to MALL (no dirty L2).
__device__ __forceinline__ void astore(__hip_bfloat16* p, u64 v) {
  __hip_atomic_store((u64*)p, v, __ATOMIC_RELAXED, __HIP_MEMORY_SCOPE_AGENT);
}
__device__ __forceinline__ unsigned int aload32(const unsigned int* p) {
  return __hip_atomic_load(p, __ATOMIC_RELAXED, __HIP_MEMORY_SCOPE_AGENT);
}
__device__ __forceinline__ void astore32(unsigned int* p, unsigned int v) {
  __hip_atomic_store(p, v, __ATOMIC_RELAXED, __HIP_MEMORY_SCOPE_AGENT);
}
__device__ __forceinline__ unsigned short f2bf(float f) {
  __hip_bfloat16 h = __float2bfloat16(f);
  unsigned short s; __builtin_memcpy(&s, &h, 2); return s;
}

// ---------------- elementwise converts ----------------
__global__ void cvt_f32_bf16(const float* __restrict__ src, __hip_bfloat16* __restrict__ dst, int n) {
  for (int i = blockIdx.x*blockDim.x + threadIdx.x; i < n; i += gridDim.x*blockDim.x)
    dst[i] = __float2bfloat16(src[i]);
}

// x [B][S][I] f32 -> xb [S][B][I] bf16
__global__ void xpose_x(const float* __restrict__ x, __hip_bfloat16* __restrict__ xb) {
  const int total = B_*S_*I_;
  for (int d = blockIdx.x*blockDim.x + threadIdx.x; d < total; d += gridDim.x*blockDim.x) {
    int i = d & (I_-1);
    int b = (d >> 8) & (B_-1);
    int s = d >> 13;
    xb[d] = __float2bfloat16(x[((size_t)b*S_ + s)*I_ + i]);
  }
}

// ---------------- output GEMM: out[(b*S+s)*O+n] = A[m]*Yw^T + Yb ----------------
__global__ __launch_bounds__(256) void gemm_out(
    const __hip_bfloat16* __restrict__ A,   // [M][H] = hs2 slots 1..512
    const __hip_bfloat16* __restrict__ W,   // [O][H]
    float* __restrict__ dstf,
    const float* __restrict__ bias)
{
  __shared__ __hip_bfloat16 As[128][32];
  __shared__ __hip_bfloat16 Ws[64][32];
  const int tid  = threadIdx.x;
  const int wid  = tid >> 6, lane = tid & 63;
  const int m0   = blockIdx.y * 128, n0 = blockIdx.x * 64;
  const int col  = lane & 15, kl = (lane >> 4) * 8;
  const int lrow = tid >> 2, lcol = (tid & 3) * 8;
  f32x4 acc[2][4] = {};

  for (int k0 = 0; k0 < H_; k0 += 32) {
    __syncthreads();
    *(bf16x8*)&As[lrow][lcol]    = *(const bf16x8*)&A[(size_t)(m0+lrow)*H_    + k0 + lcol];
    *(bf16x8*)&As[lrow+64][lcol] = *(const bf16x8*)&A[(size_t)(m0+lrow+64)*H_ + k0 + lcol];
    *(bf16x8*)&Ws[lrow][lcol]    = *(const bf16x8*)&W[(size_t)(n0+lrow)*H_    + k0 + lcol];
    __syncthreads();
    bf16x8 a0 = *(const bf16x8*)&As[wid*32 + col][kl];
    bf16x8 a1 = *(const bf16x8*)&As[wid*32 + 16 + col][kl];
#pragma unroll
    for (int nt = 0; nt < 4; ++nt) {
      bf16x8 bw = *(const bf16x8*)&Ws[nt*16 + col][kl];
      acc[0][nt] = MFMA16(a0, bw, acc[0][nt]);
      acc[1][nt] = MFMA16(a1, bw, acc[1][nt]);
    }
  }
#pragma unroll
  for (int mt = 0; mt < 2; ++mt)
#pragma unroll
    for (int nt = 0; nt < 4; ++nt)
#pragma unroll
      for (int j = 0; j < 4; ++j) {
        int m = m0 + wid*32 + mt*16 + (lane>>4)*4 + j;
        int n = n0 + nt*16 + col;
        int s = m >> 5, b = m & 31;
        dstf[((size_t)b*S_ + s)*O_ + n] = acc[mt][nt][j] + bias[n];
      }
}

// ---------------- fused 2-layer persistent recurrence ----------------
// Blocks 0..63 = layer 0, 64..127 = layer 1 (one step behind).
// Broadcast state in per-step UNIQUE slots (sc1 writes, cached reads).
// Flags: ONE PER 256B LINE (stride FSTR uints) so 64 producer stores hit 64
// distinct MALL lines in parallel and the 128 polling waves spread across 64
// lines instead of hammering 2.
// Epochs: init=1, step t: phase A done -> 2t+2, phase B done -> 2t+3.
struct R2Args {
  const __hip_bfloat16 *xb;                      // [S][B][I]
  const __hip_bfloat16 *w1_0, *w2_0, *w1_1, *w2_1;
  const float *bz0,*br0,*bg0,*bz1,*br1,*bg1;
  const float *h0;                               // [B][2][H]
  __hip_bfloat16 *hs1;                           // [S+1][B][H]
  __hip_bfloat16 *hs2;                           // [S+1][B][H]
  __hip_bfloat16 *hr1;                           // [S][B][H]
  __hip_bfloat16 *hr2;                           // [S][B][H]
  float *fin;                                    // out + OUT_ELEMS
  unsigned int *flag0, *flag1;                   // 64 flags x FSTR uints each
};

template<int LAY>
__device__ __forceinline__ void run_layer(const R2Args& a, int sub, int tid) {
  __shared__ f32x4 part[4][4][64];
  const int wid = tid >> 6, lane = tid & 63;
  const int col = lane & 15, kl = (lane >> 4) * 8;
  constexpr int K1 = LAY ? H_ : I_;     // W1 inner dim
  constexpr int NX = K1 / 128;          // x chunks per wave (8 or 2)

  unsigned int* mf = LAY ? a.flag1 : a.flag0;
  __hip_bfloat16* hsO = LAY ? a.hs2 : a.hs1;     // own h history
  __hip_bfloat16* hrO = LAY ? a.hr2 : a.hr1;     // own hr history
  const __hip_bfloat16* W2 = LAY ? a.w2_1 : a.w2_0;
  const __hip_bfloat16* W1 = LAY ? a.w1_1 : a.w1_0;

  // ---- weights into VGPRs (cached; written by earlier dispatches) ----
  bf16x8 wz2[8], wr2[8], wg2[8], wz1[NX], wr1[NX], wg1[NX];
  {
    const __hip_bfloat16* wp = W2 + (size_t)(sub*16+col)*H_ + wid*256 + kl;
#pragma unroll
    for (int kc = 0; kc < 8; ++kc) {
      wz2[kc] = *(const bf16x8*)(wp + kc*32);
      wr2[kc] = *(const bf16x8*)(wp + (size_t)H_*H_   + kc*32);
      wg2[kc] = *(const bf16x8*)(wp + (size_t)2*H_*H_ + kc*32);
    }
    const __hip_bfloat16* qp = W1 + (size_t)(sub*16+col)*K1 + wid*(K1/4) + kl;
#pragma unroll
    for (int c = 0; c < NX; ++c) {
      wz1[c] = *(const bf16x8*)(qp + c*32);
      wr1[c] = *(const bf16x8*)(qp + (size_t)H_*K1   + c*32);
      wg1[c] = *(const bf16x8*)(qp + (size_t)2*H_*K1 + c*32);
    }
  }

  // ---- persistent state (epilogue threads wid<2) ----
  const int b   = wid*16 + (lane & 15);
  const int hh0 = sub*16 + (lane >> 4)*4;
  float hreg[4] = {0,0,0,0}, zreg[4] = {0,0,0,0};
  f32x4 bz4 = {0,0,0,0}, br4 = {0,0,0,0}, bg4 = {0,0,0,0};
  if (wid < 2) {
    bz4 = *(const f32x4*)((LAY ? a.bz1 : a.bz0) + hh0);
    br4 = *(const f32x4*)((LAY ? a.br1 : a.br0) + hh0);
    bg4 = *(const f32x4*)((LAY ? a.bg1 : a.bg0) + hh0);
    f32x4 h4 = *(const f32x4*)(a.h0 + (size_t)b*2048 + LAY*1024 + hh0);
#pragma unroll
    for (int j = 0; j < 4; ++j) hreg[j] = h4[j];
  }
  if (tid < 128) {   // init slot 0 of own h history (sc1)
    int bb = tid >> 2, hi = sub*16 + (tid & 3)*4;
    f32x4 v = *(const f32x4*)(a.h0 + (size_t)bb*2048 + LAY*1024 + hi);
    u64 pk = 0;
#pragma unroll
    for (int j = 0; j < 4; ++j) pk |= (u64)f2bf(v[j]) << (16*j);
    astore(&hsO[(size_t)bb*H_ + hi], pk);
  }
  __syncthreads();
  if (tid == 0) astore32(&mf[sub*FSTR], 1u);

  for (int t = 0; t < S_; ++t) {
    f32x4 az0 = {0,0,0,0}, az1 = {0,0,0,0};
    f32x4 ar0 = {0,0,0,0}, ar1 = {0,0,0,0};
    f32x4 ag0 = {0,0,0,0}, ag1 = {0,0,0,0};

    // ---- L0: x-pass entirely before the wait (input always ready) ----
    if (LAY == 0) {
      const __hip_bfloat16* p0 = a.xb + (size_t)t*(B_*K1) + (size_t)col*K1 + wid*(K1/4) + kl;
      const __hip_bfloat16* p1 = p0 + (size_t)16*K1;
      bf16x8 xs0[NX], xs1[NX];
#pragma unroll
      for (int c = 0; c < NX; ++c) {
        xs0[c] = *(const bf16x8*)(p0 + c*32);
        xs1[c] = *(const bf16x8*)(p1 + c*32);
      }
#pragma unroll
      for (int c = 0; c < NX; ++c) {
        az0 = MFMA16(wz1[c], xs0[c], az0);  az1 = MFMA16(wz1[c], xs1[c], az1);
        ar0 = MFMA16(wr1[c], xs0[c], ar0);  ar1 = MFMA16(wr1[c], xs1[c], ar1);
        ag0 = MFMA16(wg1[c], xs0[c], ag0);  ag1 = MFMA16(wg1[c], xs1[c], ag1);
      }
    }

    // ---- waits: own h(t-1) published; L1 also needs hs1 slot t+1 from L0 ----
    if (wid == 0) {
      unsigned int tgt = 2*t + 1;
      while (aload32(&mf[lane*FSTR]) < tgt) __builtin_amdgcn_s_sleep(2);
    } else if (LAY == 1 && wid == 1) {
      unsigned int tgt = 2*t + 3;
      while (aload32(&a.flag0[lane*FSTR]) < tgt) __builtin_amdgcn_s_sleep(2);
    }
    __syncthreads();

    // ---- phase A: cached bursts (XCD-L2 shared), then MFMAs ----
    {
      const __hip_bfloat16* hp0 = hsO + (size_t)t*BH_ + (size_t)col*H_ + wid*256 + kl;
      const __hip_bfloat16* hp1 = hp0 + (size_t)16*H_;
      V4 HV0[8], HV1[8];
      if (LAY == 1) {
        const __hip_bfloat16* p0 = a.hs1 + (size_t)(t+1)*BH_ + (size_t)col*H_ + wid*256 + kl;
        const __hip_bfloat16* p1 = p0 + (size_t)16*H_;
        V4 XV0[8], XV1[8];
        LD8C(p0, XV0); LD8C(p1, XV1);
        LD8C(hp0, HV0); LD8C(hp1, HV1);
        WAITV();
#pragma unroll
        for (int c = 0; c < 8; ++c) {
          az0 = MFMA16(wz1[c], XV0[c].b, az0);  az1 = MFMA16(wz1[c], XV1[c].b, az1);
          ar0 = MFMA16(wr1[c], XV0[c].b, ar0);  ar1 = MFMA16(wr1[c], XV1[c].b, ar1);
          ag0 = MFMA16(wg1[c], XV0[c].b, ag0);  ag1 = MFMA16(wg1[c], XV1[c].b, ag1);
        }
      } else {
        LD8C(hp0, HV0); LD8C(hp1, HV1);
        WAITV();
      }
#pragma unroll
      for (int kc = 0; kc < 8; ++kc) {
        az0 = MFMA16(wz2[kc], HV0[kc].b, az0);  az1 = MFMA16(wz2[kc], HV1[kc].b, az1);
        ar0 = MFMA16(wr2[kc], HV0[kc].b, ar0);  ar1 = MFMA16(wr2[kc], HV1[kc].b, ar1);
      }
    }
    part[wid][0][lane] = az0; part[wid][1][lane] = az1;
    part[wid][2][lane] = ar0; part[wid][3][lane] = ar1;
    __syncthreads();
    if (wid < 2) {
      f32x4 zs = part[0][wid][lane] + part[1][wid][lane] + part[2][wid][lane] + part[3][wid][lane];
      f32x4 rs = part[0][2+wid][lane] + part[1][2+wid][lane] + part[2][2+wid][lane] + part[3][2+wid][lane];
      u64 pk = 0;
#pragma unroll
      for (int j = 0; j < 4; ++j) {
        float z = 1.f / (1.f + __expf(-(zs[j] + bz4[j])));
        float r = 1.f / (1.f + __expf(-(rs[j] + br4[j])));
        zreg[j] = z;
        pk |= (u64)f2bf(r * hreg[j]) << (16*j);
      }
      astore(&hrO[(size_t)t*BH_ + (size_t)b*H_ + hh0], pk);
    }
    __syncthreads();                      // drains stores before flag
    if (tid == 0) astore32(&mf[sub*FSTR], 2*t + 2);
    if (wid == 0) {
      unsigned int tgt = 2*t + 2;
      while (aload32(&mf[lane*FSTR]) < tgt) __builtin_amdgcn_s_sleep(2);
    }
    __syncthreads();

    // ---- phase B: g += W2g*(r.h); h update ----
    {
      const __hip_bfloat16* hp0 = hrO + (size_t)t*BH_ + (size_t)col*H_ + wid*256 + kl;
      const __hip_bfloat16* hp1 = hp0 + (size_t)16*H_;
      V4 RV0[8], RV1[8];
      LD8C(hp0, RV0); LD8C(hp1, RV1);
      WAITV();
#pragma unroll
      for (int kc = 0; kc < 8; ++kc) {
        ag0 = MFMA16(wg2[kc], RV0[kc].b, ag0);
        ag1 = MFMA16(wg2[kc], RV1[kc].b, ag1);
      }
    }
    part[wid][0][lane] = ag0; part[wid][1][lane] = ag1;
    __syncthreads();
    if (wid < 2) {
      f32x4 gs = part[0][wid][lane] + part[1][wid][lane] + part[2][wid][lane] + part[3][wid][lane];
      u64 pk = 0; f32x4 fv;
#pragma unroll
      for (int j = 0; j < 4; ++j) {
        float g  = tanhf(gs[j] + bg4[j]);
        float hn = zreg[j]*hreg[j] + (1.f - zreg[j])*g;
        hreg[j] = hn; fv[j] = hn;
        pk |= (u64)f2bf(hn) << (16*j);
      }
      astore(&hsO[(size_t)(t+1)*BH_ + (size_t)b*H_ + hh0], pk);   // the ONLY h store
      if (t == S_-2) *(f32x4*)(a.fin + LAY*1024 + (size_t)b*2048 + hh0) = fv;
    }
    __syncthreads();                      // drains stores before flag
    if (tid == 0) astore32(&mf[sub*FSTR], 2*t + 3);
  }
}

__global__ __launch_bounds__(256, 1) void recur2(R2Args a) {
  const int lay = blockIdx.x >> 6, sub = blockIdx.x & 63;
  if (lay == 0) run_layer<0>(a, sub, threadIdx.x);
  else          run_layer<1>(a, sub, threadIdx.x);
}

// ---------------- host ----------------
extern "C" void kernel_launch(void* const* d_in, const int* in_sizes, int n_in,
                              void* d_out, int out_size, void* d_ws, size_t ws_size,
                              hipStream_t stream) {
  (void)in_sizes; (void)n_in; (void)out_size; (void)ws_size;
  const float* x     = (const float*)d_in[0];
  const float* hid0  = (const float*)d_in[1];
  const float* z1_0  = (const float*)d_in[2];
  const float* z2_0  = (const float*)d_in[3];
  const float* z2b_0 = (const float*)d_in[4];
  const float* r1_0  = (const float*)d_in[5];
  const float* r2_0  = (const float*)d_in[6];
  const float* r2b_0 = (const float*)d_in[7];
  const float* g1_0  = (const float*)d_in[8];
  const float* g2_0  = (const float*)d_in[9];
  const float* g2b_0 = (const float*)d_in[10];
  const float* z1_1  = (const float*)d_in[11];
  const float* z2_1  = (const float*)d_in[12];
  const float* z2b_1 = (const float*)d_in[13];
  const float* r1_1  = (const float*)d_in[14];
  const float* r2_1  = (const float*)d_in[15];
  const float* r2b_1 = (const float*)d_in[16];
  const float* g1_1  = (const float*)d_in[17];
  const float* g2_1  = (const float*)d_in[18];
  const float* g2b_1 = (const float*)d_in[19];
  const float* Yw    = (const float*)d_in[20];
  const float* Yb    = (const float*)d_in[21];
  float* out = (float*)d_out;

  char* ws = (char*)d_ws;
  size_t off = 0;
  auto alloc = [&](size_t bytes) -> void* {
    void* p = ws + off; off += (bytes + 255) & ~(size_t)255; return p;
  };
  __hip_bfloat16* hs1   = (__hip_bfloat16*)alloc((size_t)(S_+1)*BH_*2);  // 33.6 MB
  __hip_bfloat16* hs2   = (__hip_bfloat16*)alloc((size_t)(S_+1)*BH_*2);  // 33.6 MB
  __hip_bfloat16* hr1   = (__hip_bfloat16*)alloc((size_t)S_*BH_*2);      // 32 MB
  __hip_bfloat16* hr2   = (__hip_bfloat16*)alloc((size_t)S_*BH_*2);      // 32 MB
  __hip_bfloat16* xb    = (__hip_bfloat16*)alloc((size_t)M_*I_*2);       // 8 MB
  __hip_bfloat16* w1p0  = (__hip_bfloat16*)alloc((size_t)3*H_*I_*2);
  __hip_bfloat16* w1p1  = (__hip_bfloat16*)alloc((size_t)3*H_*H_*2);
  __hip_bfloat16* w2p0  = (__hip_bfloat16*)alloc((size_t)3*H_*H_*2);
  __hip_bfloat16* w2p1  = (__hip_bfloat16*)alloc((size_t)3*H_*H_*2);
  __hip_bfloat16* ywp   = (__hip_bfloat16*)alloc((size_t)O_*H_*2);
  unsigned int*   bars  = (unsigned int*)  alloc(2*64*FSTR*4);   // 32 KB padded flags

  hipMemsetAsync(bars, 0, 2*64*FSTR*4, stream);

  hipLaunchKernelGGL(xpose_x, dim3(2048), dim3(256), 0, stream, x, xb);
  auto CVT = [&](const float* s, __hip_bfloat16* d, int n) {
    hipLaunchKernelGGL(cvt_f32_bf16, dim3(512), dim3(256), 0, stream, s, d, n);
  };
  CVT(z1_0, w1p0,            H_*I_);
  CVT(r1_0, w1p0 + H_*I_,    H_*I_);
  CVT(g1_0, w1p0 + 2*H_*I_,  H_*I_);
  CVT(z2_0, w2p0,            H_*H_);
  CVT(r2_0, w2p0 + H_*H_,    H_*H_);
  CVT(g2_0, w2p0 + 2*H_*H_,  H_*H_);
  CVT(z1_1, w1p1,            H_*H_);
  CVT(r1_1, w1p1 + H_*H_,    H_*H_);
  CVT(g1_1, w1p1 + 2*H_*H_,  H_*H_);
  CVT(z2_1, w2p1,            H_*H_);
  CVT(r2_1, w2p1 + H_*H_,    H_*H_);
  CVT(g2_1, w2p1 + 2*H_*H_,  H_*H_);
  CVT(Yw,   ywp,             O_*H_);

  R2Args ra;
  ra.xb = xb;
  ra.w1_0 = w1p0; ra.w2_0 = w2p0; ra.w1_1 = w1p1; ra.w2_1 = w2p1;
  ra.bz0 = z2b_0; ra.br0 = r2b_0; ra.bg0 = g2b_0;
  ra.bz1 = z2b_1; ra.br1 = r2b_1; ra.bg1 = g2b_1;
  ra.h0 = hid0;
  ra.hs1 = hs1; ra.hs2 = hs2; ra.hr1 = hr1; ra.hr2 = hr2;
  ra.fin = out + OUT_ELEMS;
  ra.flag0 = bars; ra.flag1 = bars + 64*FSTR;
  hipLaunchKernelGGL(recur2, dim3(128), dim3(256), 0, stream, ra);

  // output projection + bias (A = hs2 slots 1..512)
  hipLaunchKernelGGL(gemm_out, dim3(4, 128), dim3(256), 0, stream,
                     hs2 + BH_, ywp, out, Yb);
}